// Round 4
// baseline (12255.878 us; speedup 1.0000x reference)
//
#include <hip/hip_runtime.h>
#include <math.h>

#define LEAK 0.2f

typedef __attribute__((ext_vector_type(8))) short bf16x8;
typedef __attribute__((ext_vector_type(4))) float f32x4;

__device__ __forceinline__ unsigned short f2bf(float f) {
  unsigned u = __float_as_uint(f);
  u += 0x7FFFu + ((u >> 16) & 1u);
  return (unsigned short)(u >> 16);
}
__device__ __forceinline__ float bf2f(unsigned short s) {
  return __uint_as_float(((unsigned)s) << 16);
}
__device__ __forceinline__ unsigned pack2(float a, float b) {
  return (unsigned)f2bf(a) | ((unsigned)f2bf(b) << 16);
}

#define MFMA16(a, b, c) __builtin_amdgcn_mfma_f32_16x16x32_bf16(a, b, c, 0, 0, 0)

// ============================================================================
// conv1: 1x1 conv 512->32 on 254x254. Output TRANSPOSED f32 [n][254*254][32]
// + fused per-channel partial sums (strip = n*64 + blockIdx.x, S=512).
// ============================================================================
__global__ __launch_bounds__(256) void conv1_kernel(
    const float* __restrict__ h, const float* __restrict__ w,
    float* __restrict__ xT, float* __restrict__ part)
{
  __shared__ float wt[256 * 32];
  __shared__ float red[4][32][2];
  const int n  = blockIdx.y;
  const int r0 = blockIdx.x * 4;
  const int ix = threadIdx.x;
  const bool lanev = (ix < 254);
  const bool rv2 = (r0 + 2) < 254, rv3 = (r0 + 3) < 254;

  float acc[4][32];
#pragma unroll
  for (int r = 0; r < 4; ++r)
#pragma unroll
    for (int o = 0; o < 32; ++o) acc[r][o] = 0.f;

  const float* hp = h + (size_t)n * 512 * 64516 + (size_t)r0 * 254 + ix;

  for (int half = 0; half < 2; ++half) {
    const int cbase = half * 256;
    for (int i = threadIdx.x; i < 256 * 32; i += 256) {
      int c = i >> 5, o = i & 31;
      wt[i] = w[(size_t)o * 512 + cbase + c];
    }
    __syncthreads();
    if (lanev) {
#pragma unroll 4
      for (int c = 0; c < 256; ++c) {
        const float* pc = hp + (size_t)(cbase + c) * 64516;
        float vr[4];
        vr[0] = pc[0];
        vr[1] = pc[254];
        vr[2] = rv2 ? pc[2 * 254] : 0.f;
        vr[3] = rv3 ? pc[3 * 254] : 0.f;
        const float4* wp = (const float4*)&wt[c * 32];
#pragma unroll
        for (int q = 0; q < 8; ++q) {
          float4 w4 = wp[q];
#pragma unroll
          for (int r = 0; r < 4; ++r) {
            acc[r][4 * q + 0] = fmaf(vr[r], w4.x, acc[r][4 * q + 0]);
            acc[r][4 * q + 1] = fmaf(vr[r], w4.y, acc[r][4 * q + 1]);
            acc[r][4 * q + 2] = fmaf(vr[r], w4.z, acc[r][4 * q + 2]);
            acc[r][4 * q + 3] = fmaf(vr[r], w4.w, acc[r][4 * q + 3]);
          }
        }
      }
    }
    __syncthreads();
  }

  // write transposed: xT[n][(row*254+col)][32]
  if (lanev) {
#pragma unroll
    for (int r = 0; r < 4; ++r) {
      if (r0 + r < 254) {
        float* dst = xT + ((size_t)n * 64516 + (size_t)(r0 + r) * 254 + ix) * 32;
        const float4* a4 = (const float4*)&acc[r][0];
#pragma unroll
        for (int q = 0; q < 8; ++q) ((float4*)dst)[q] = a4[q];
      }
    }
  }

  // fused per-channel partial sums (invalid lanes/rows hold acc==0)
  const int wv = ix >> 6;
#pragma unroll 4
  for (int o = 0; o < 32; ++o) {
    float s = 0.f, q = 0.f;
#pragma unroll
    for (int r = 0; r < 4; ++r) { float v = acc[r][o]; s += v; q += v * v; }
    for (int off = 32; off; off >>= 1) {
      s += __shfl_down(s, off);
      q += __shfl_down(q, off);
    }
    if ((ix & 63) == 0) { red[wv][o][0] = s; red[wv][o][1] = q; }
  }
  __syncthreads();
  if (ix < 32) {
    float s = red[0][ix][0] + red[1][ix][0] + red[2][ix][0] + red[3][ix][0];
    float q = red[0][ix][1] + red[1][ix][1] + red[2][ix][1] + red[3][ix][1];
    const int strip = n * 64 + blockIdx.x;
    part[((size_t)ix * 512 + strip) * 2]     = s;
    part[((size_t)ix * 512 + strip) * 2 + 1] = q;
  }
}

// ============================================================================
// cbn1T: normalize conv1 output (incl. the 256^2 zero ring!) and write padded
// transposed bf16 T2 [n][258*258][32].
// ============================================================================
__global__ __launch_bounds__(256) void cbn1T_kernel(
    const float* __restrict__ xT, const float* __restrict__ stats,
    const float* __restrict__ e1, const int* __restrict__ objs,
    unsigned short* __restrict__ T2)
{
  __shared__ float st[32][4];
  const int n = blockIdx.y;
  if (threadIdx.x < 32) {
    int y = objs[n];
    st[threadIdx.x][0] = stats[threadIdx.x];
    st[threadIdx.x][1] = stats[32 + threadIdx.x];
    st[threadIdx.x][2] = e1[(size_t)y * 64 + threadIdx.x];
    st[threadIdx.x][3] = e1[(size_t)y * 64 + 32 + threadIdx.x];
  }
  __syncthreads();
  const int pix = blockIdx.x * 256 + threadIdx.x;   // 0..65535 over 256^2
  const int r = pix >> 8, c = pix & 255;
  const bool inter = (r >= 1 && r <= 254 && c >= 1 && c <= 254);
  const float* src = xT + ((size_t)n * 64516 + (size_t)(r - 1) * 254 + (c - 1)) * 32;
  unsigned short* dst = T2 + ((size_t)n * 66564 + (size_t)(r + 1) * 258 + (c + 1)) * 32;
  unsigned outw[16];
#pragma unroll
  for (int q = 0; q < 8; ++q) {
    float v[4];
    if (inter) { float4 t = ((const float4*)src)[q]; v[0]=t.x; v[1]=t.y; v[2]=t.z; v[3]=t.w; }
    else       { v[0]=v[1]=v[2]=v[3]=0.f; }
#pragma unroll
    for (int j = 0; j < 4; ++j) {
      int ch = q * 4 + j;
      float z = (v[j] - st[ch][0]) * st[ch][1] * st[ch][2] + st[ch][3];
      v[j] = z >= 0.f ? z : LEAK * z;
    }
    outw[2 * q]     = pack2(v[0], v[1]);
    outw[2 * q + 1] = pack2(v[2], v[3]);
  }
  uint4* d4 = (uint4*)dst;
#pragma unroll
  for (int q = 0; q < 4; ++q)
    d4[q] = make_uint4(outw[4*q], outw[4*q+1], outw[4*q+2], outw[4*q+3]);
}

// ============================================================================
// weight prep: [O][C][TAPS] f32 -> [tap][O][C] bf16
// ============================================================================
__global__ __launch_bounds__(256) void wprep_kernel(
    const float* __restrict__ w, unsigned short* __restrict__ dst, int O, int C, int TAPS)
{
  int i = blockIdx.x * 256 + threadIdx.x;
  int tot = O * C * TAPS;
  if (i < tot) {
    int o = i / (C * TAPS);
    int r = i - o * C * TAPS;
    int c = r / TAPS, tap = r - c * TAPS;
    dst[((size_t)tap * O + o) * C + c] = f2bf(w[i]);
  }
}

// ============================================================================
// conv4T: 4x4 stride-2 pad-1 conv, stage-free (B direct from padded bf16
// transposed input). Out: raw f32 [n][H*H][O].
// Block: 4 waves (2 wm x 2 wn), 64 o x 64 pixels. Grid (O/64, H*H/64, 8).
// ============================================================================
template <int C, int O, int H>
__global__ __launch_bounds__(256) void conv4T_kernel(
    const unsigned short* __restrict__ Tin, const unsigned short* __restrict__ wb,
    float* __restrict__ raw)
{
  constexpr int HIN2 = 2 * H + 2;
  constexpr int KC = C / 32;
  constexpr int LOGH = (H == 128 ? 7 : (H == 64 ? 6 : (H == 32 ? 5 : 4)));
  const int o0 = blockIdx.x * 64;
  const int strip = blockIdx.y;
  const int n = blockIdx.z;
  const int tid = threadIdx.x, lane = tid & 63, wid = tid >> 6;
  const int wm = wid >> 1, wn = wid & 1;
  const int ln15 = lane & 15, kg = lane >> 4;
  const unsigned short* inb = Tin + (size_t)n * (HIN2 * HIN2) * C;

  f32x4 acc[2][2];
#pragma unroll
  for (int m = 0; m < 2; ++m)
#pragma unroll
    for (int nt = 0; nt < 2; ++nt) acc[m][nt] = (f32x4){0.f, 0.f, 0.f, 0.f};

  const int gp0 = strip * 64 + (wn * 2 + 0) * 16;
  const int gp1 = strip * 64 + (wn * 2 + 1) * 16;
  const int r_0 = gp0 >> LOGH, c_0 = (gp0 & (H - 1)) + ln15;
  const int r_1 = gp1 >> LOGH, c_1 = (gp1 & (H - 1)) + ln15;

  for (int kc = 0; kc < KC; ++kc) {
    const int cb = kc * 32 + kg * 8;
#pragma unroll
    for (int tap = 0; tap < 16; ++tap) {
      const int ky = tap >> 2, kx = tap & 3;
      const unsigned short* ap = wb + ((size_t)tap * O + o0 + wm * 32 + ln15) * C + cb;
      bf16x8 a0 = *(const bf16x8*)ap;
      bf16x8 a1 = *(const bf16x8*)(ap + (size_t)16 * C);
      bf16x8 b0 = *(const bf16x8*)(inb + (size_t)((2 * r_0 + ky) * HIN2 + 2 * c_0 + kx) * C + cb);
      bf16x8 b1 = *(const bf16x8*)(inb + (size_t)((2 * r_1 + ky) * HIN2 + 2 * c_1 + kx) * C + cb);
      acc[0][0] = MFMA16(a0, b0, acc[0][0]);
      acc[1][0] = MFMA16(a1, b0, acc[1][0]);
      acc[0][1] = MFMA16(a0, b1, acc[0][1]);
      acc[1][1] = MFMA16(a1, b1, acc[1][1]);
    }
  }

#pragma unroll
  for (int mf = 0; mf < 2; ++mf) {
    const int o = o0 + wm * 32 + mf * 16 + kg * 4;
#pragma unroll
    for (int nt = 0; nt < 2; ++nt) {
      const int gp = strip * 64 + (wn * 2 + nt) * 16 + ln15;
      *(f32x4*)(raw + ((size_t)n * (H * H) + gp) * O + o) = acc[mf][nt];
    }
  }
}

// ============================================================================
// meanvarT: per-channel partial sums over raw f32 [n][npix][C].
// Grid (SPLITS, 8); strip s = n*SPLITS + bx; S = SPLITS*8.
// ============================================================================
template <int C>
__global__ __launch_bounds__(256) void meanvarT_kernel(
    const float* __restrict__ raw, float* __restrict__ part, int npix, int SPLITS)
{
  constexpr int C8 = C / 8, PL = 256 / C8;
  __shared__ float red[256][8][2];
  const int n = blockIdx.y, bx = blockIdx.x;
  const int c8 = threadIdx.x & (C8 - 1), pl = threadIdx.x / C8;
  const int LEN = npix / SPLITS;
  const int start = bx * LEN;
  const float* base = raw + (size_t)n * npix * C + c8 * 8;
  float s[8], q[8];
#pragma unroll
  for (int k = 0; k < 8; ++k) { s[k] = 0.f; q[k] = 0.f; }
  for (int i = start + pl; i < start + LEN; i += PL) {
    const float4* p = (const float4*)(base + (size_t)i * C);
    float4 v0 = p[0], v1 = p[1];
    float vv[8] = {v0.x, v0.y, v0.z, v0.w, v1.x, v1.y, v1.z, v1.w};
#pragma unroll
    for (int k = 0; k < 8; ++k) { s[k] += vv[k]; q[k] += vv[k] * vv[k]; }
  }
#pragma unroll
  for (int k = 0; k < 8; ++k) { red[threadIdx.x][k][0] = s[k]; red[threadIdx.x][k][1] = q[k]; }
  __syncthreads();
  const int S = SPLITS * 8;
  for (int c = threadIdx.x; c < C; c += 256) {
    int cc8 = c >> 3, k = c & 7;
    float ss = 0.f, qq = 0.f;
    for (int p2 = 0; p2 < PL; ++p2) {
      ss += red[p2 * C8 + cc8][k][0];
      qq += red[p2 * C8 + cc8][k][1];
    }
    const int sidx = n * SPLITS + bx;
    part[((size_t)c * S + sidx) * 2]     = ss;
    part[((size_t)c * S + sidx) * 2 + 1] = qq;
  }
}

// ---------------- finalize stats: part[C][S][2] -> stats[2][C] --------------
__global__ __launch_bounds__(64) void fin_kernel(
    const float* __restrict__ part, float* __restrict__ stats, int C, int S, float invN)
{
  int c = blockIdx.x * 64 + threadIdx.x;
  if (c >= C) return;
  float sum = 0.f, sq = 0.f;
  for (int s = 0; s < S; ++s) {
    sum += part[((size_t)c * S + s) * 2];
    sq  += part[((size_t)c * S + s) * 2 + 1];
  }
  float mean = sum * invN;
  float var = sq * invN - mean * mean;
  stats[c] = mean;
  stats[C + c] = rsqrtf(var + 1e-5f);
}

// ============================================================================
// cbnT: read raw f32 [n][H*H][C], normalize (+lrelu), write padded bf16
// [nmap][(H+2P)^2][CSO] at channel offset 0. Grid (H*H/64, 8).
// ============================================================================
template <int C, int H, int P2, int CSO, bool LRELU, bool LMAP>
__global__ __launch_bounds__(256) void cbnT_kernel(
    const float* __restrict__ raw, const float* __restrict__ stats,
    const float* __restrict__ embed, const int* __restrict__ objs,
    unsigned short* __restrict__ Tout)
{
  constexpr int W2 = H + 2 * P2;
  constexpr int LOGH = (H == 128 ? 7 : (H == 64 ? 6 : (H == 32 ? 5 : 4)));
  const int n = blockIdx.y;
  const int y = objs[n];
  const int pix = blockIdx.x * 64 + (threadIdx.x >> 2);
  const int r = pix >> LOGH, c = pix & (H - 1);
  const float* src = raw + ((size_t)n * (H * H) + pix) * C;
  const size_t nb = LMAP ? (size_t)((n & 1) * 4 + (n >> 1)) * (W2 * W2) * CSO
                         : (size_t)n * (W2 * W2) * CSO;
  unsigned short* dst = Tout + nb + ((size_t)(r + P2) * W2 + c + P2) * CSO;
  const float* gam = embed + (size_t)y * 2 * C;
  const float* bet = gam + C;
  for (int cs = (threadIdx.x & 3); cs < C / 8; cs += 4) {
    float4 m0 = ((const float4*)stats)[cs * 2],     m1 = ((const float4*)stats)[cs * 2 + 1];
    float4 s0 = ((const float4*)(stats + C))[cs * 2], s1 = ((const float4*)(stats + C))[cs * 2 + 1];
    float4 g0 = ((const float4*)gam)[cs * 2], g1 = ((const float4*)gam)[cs * 2 + 1];
    float4 b0 = ((const float4*)bet)[cs * 2], b1 = ((const float4*)bet)[cs * 2 + 1];
    float4 v0 = ((const float4*)src)[cs * 2], v1 = ((const float4*)src)[cs * 2 + 1];
    float o_[8];
    o_[0] = (v0.x - m0.x) * s0.x * g0.x + b0.x;
    o_[1] = (v0.y - m0.y) * s0.y * g0.y + b0.y;
    o_[2] = (v0.z - m0.z) * s0.z * g0.z + b0.z;
    o_[3] = (v0.w - m0.w) * s0.w * g0.w + b0.w;
    o_[4] = (v1.x - m1.x) * s1.x * g1.x + b1.x;
    o_[5] = (v1.y - m1.y) * s1.y * g1.y + b1.y;
    o_[6] = (v1.z - m1.z) * s1.z * g1.z + b1.z;
    o_[7] = (v1.w - m1.w) * s1.w * g1.w + b1.w;
    if (LRELU) {
#pragma unroll
      for (int k = 0; k < 8; ++k) o_[k] = o_[k] >= 0.f ? o_[k] : LEAK * o_[k];
    }
    ((uint4*)dst)[cs] = make_uint4(pack2(o_[0], o_[1]), pack2(o_[2], o_[3]),
                                   pack2(o_[4], o_[5]), pack2(o_[6], o_[7]));
  }
}

// ============================================================================
// conv5L: 5x5 s1 p2 conv on 16x16 (ConvLSTM), stage-free.
// Block: 4 waves = WM x WN over (WM*32 o) x 256 pixels. Grid (O/(WM*32), 4, KSPLIT).
// Out partials pp[ks][b][pix][O] f32.
// ============================================================================
template <int O, int C, int CS, int WM, int WN, int NCHUNK>
__global__ __launch_bounds__(256) void conv5L_kernel(
    const unsigned short* __restrict__ Lin, const unsigned short* __restrict__ wbf,
    float* __restrict__ pp)
{
  constexpr int FN = 16 / WN;
  const int o0 = blockIdx.x * (WM * 32);
  const int b = blockIdx.y, ks = blockIdx.z;
  const int tid = threadIdx.x, lane = tid & 63, wid = tid >> 6;
  const int wm = wid / WN, wn = wid % WN;
  const int ln15 = lane & 15, kg = lane >> 4;
  const unsigned short* inb = Lin + (size_t)b * 400 * CS;

  f32x4 acc[2][FN];
#pragma unroll
  for (int m = 0; m < 2; ++m)
#pragma unroll
    for (int nt = 0; nt < FN; ++nt) acc[m][nt] = (f32x4){0.f, 0.f, 0.f, 0.f};

  for (int kc = 0; kc < NCHUNK; ++kc) {
    const int cb = (ks * NCHUNK + kc) * 32 + kg * 8;
    for (int tap = 0; tap < 25; ++tap) {
      const int ty = tap / 5, tx = tap - 5 * ty;
      const unsigned short* ap = wbf + ((size_t)tap * O + o0 + wm * 32 + ln15) * C + cb;
      bf16x8 a0 = *(const bf16x8*)ap;
      bf16x8 a1 = *(const bf16x8*)(ap + (size_t)16 * C);
#pragma unroll
      for (int nt = 0; nt < FN; ++nt) {
        const int p = (wn * FN + nt) * 16 + ln15;
        const int prow = p >> 4, pcol = p & 15;
        bf16x8 bfv = *(const bf16x8*)(inb + (size_t)((prow + ty) * 20 + pcol + tx) * CS + cb);
        acc[0][nt] = MFMA16(a0, bfv, acc[0][nt]);
        acc[1][nt] = MFMA16(a1, bfv, acc[1][nt]);
      }
    }
  }

#pragma unroll
  for (int mf = 0; mf < 2; ++mf) {
    const int o = o0 + wm * 32 + mf * 16 + kg * 4;
#pragma unroll
    for (int nt = 0; nt < FN; ++nt) {
      const int pix = (wn * FN + nt) * 16 + ln15;
      *(f32x4*)(pp + (((size_t)(ks * 4 + b)) * 256 + pix) * O + o) = acc[mf][nt];
    }
  }
}

// ============================================================================
// lstm_pointT: sum K-partials, gates -> (c,h). h written as bf16 into the
// transposed padded buffers (own layer t+1 slot + next layer x slot), and/or
// f32 NCHW d_out. cT is f32 [b][pix][Hc].
// ============================================================================
template <int Hc, int CS, int CX, int CSN>
__global__ __launch_bounds__(256) void lstm_pointT_kernel(
    const float* __restrict__ pp, int KS, const float* __restrict__ bias,
    float* __restrict__ cT, unsigned short* __restrict__ own,
    unsigned short* __restrict__ nxt, float* __restrict__ fout)
{
  constexpr int C4 = Hc / 4;
  constexpr int O = 4 * Hc;
  constexpr int LOGC4 = (C4 == 32 ? 5 : 4);
  const int i = blockIdx.x * 256 + threadIdx.x;
  const int c4 = i & (C4 - 1);
  const int pix = (i >> LOGC4) & 255;
  const int b = i >> (LOGC4 + 8);

  float g[4][4];
#pragma unroll
  for (int gt = 0; gt < 4; ++gt)
#pragma unroll
    for (int j = 0; j < 4; ++j) g[gt][j] = 0.f;

  for (int ks = 0; ks < KS; ++ks) {
    const float* base = pp + (((size_t)(ks * 4 + b)) * 256 + pix) * O + c4 * 4;
#pragma unroll
    for (int gt = 0; gt < 4; ++gt) {
      float4 v = *(const float4*)(base + gt * Hc);
      g[gt][0] += v.x; g[gt][1] += v.y; g[gt][2] += v.z; g[gt][3] += v.w;
    }
  }
#pragma unroll
  for (int gt = 0; gt < 4; ++gt) {
    float4 bv = *(const float4*)(bias + gt * Hc + c4 * 4);
    g[gt][0] += bv.x; g[gt][1] += bv.y; g[gt][2] += bv.z; g[gt][3] += bv.w;
  }

  float* cp = cT + ((size_t)b * 256 + pix) * Hc + c4 * 4;
  float4 cold = *(const float4*)cp;
  float co[4] = {cold.x, cold.y, cold.z, cold.w};
  float hn[4];
#pragma unroll
  for (int j = 0; j < 4; ++j) {
    float si = 1.f / (1.f + expf(-g[0][j]));
    float sf = 1.f / (1.f + expf(-g[1][j]));
    float so = 1.f / (1.f + expf(-g[2][j]));
    float cn = sf * co[j] + si * tanhf(g[3][j]);
    co[j] = cn;
    hn[j] = so * tanhf(cn);
  }
  *(float4*)cp = make_float4(co[0], co[1], co[2], co[3]);

  const int prow = pix >> 4, pcol = pix & 15;
  const int ppix = (prow + 2) * 20 + pcol + 2;
  uint2 hb = make_uint2(pack2(hn[0], hn[1]), pack2(hn[2], hn[3]));
  if (own) *(uint2*)(own + ((size_t)b * 400 + ppix) * CS + CX + c4 * 4) = hb;
  if (nxt) *(uint2*)(nxt + ((size_t)b * 400 + ppix) * CSN + c4 * 4) = hb;
  if (fout) {
#pragma unroll
    for (int j = 0; j < 4; ++j)
      fout[((size_t)b * Hc + c4 * 4 + j) * 256 + pix] = hn[j];
  }
}

// ============================================================================
extern "C" void kernel_launch(void* const* d_in, const int* in_sizes, int n_in,
                              void* d_out, int out_size, void* d_ws, size_t ws_size,
                              hipStream_t stream)
{
  const float* h    = (const float*)d_in[0];
  const int*   objs = (const int*)  d_in[1];
  const float* c1w  = (const float*)d_in[3];
  const float* c2w  = (const float*)d_in[4];
  const float* c3w  = (const float*)d_in[5];
  const float* c4w  = (const float*)d_in[6];
  const float* c5w  = (const float*)d_in[7];
  const float* e1   = (const float*)d_in[8];
  const float* e2   = (const float*)d_in[9];
  const float* e3   = (const float*)d_in[10];
  const float* e4   = (const float*)d_in[11];
  const float* e5   = (const float*)d_in[12];
  const float* lw0  = (const float*)d_in[13];
  const float* lb0  = (const float*)d_in[14];
  const float* lw1  = (const float*)d_in[15];
  const float* lb1  = (const float*)d_in[16];
  const float* lw2  = (const float*)d_in[17];
  const float* lb2  = (const float*)d_in[18];

  char* p = (char*)d_ws;
  auto alloc = [&](size_t bytes) { char* r = p; p += (bytes + 255) & ~(size_t)255; return r; };
  float* x1T  = (float*)alloc((size_t)8 * 64516 * 32 * 4);
  float* raw2 = (float*)alloc((size_t)8 * 16384 * 64 * 4);
  float* raw3 = (float*)alloc((size_t)8 * 4096 * 128 * 4);
  float* raw4 = (float*)alloc((size_t)8 * 1024 * 256 * 4);
  float* raw5 = (float*)alloc((size_t)8 * 256 * 512 * 4);
  unsigned short* T2 = (unsigned short*)alloc((size_t)8 * 66564 * 32 * 2);
  unsigned short* T3 = (unsigned short*)alloc((size_t)8 * 16900 * 64 * 2);
  unsigned short* T4 = (unsigned short*)alloc((size_t)8 * 4356 * 128 * 2);
  unsigned short* T5 = (unsigned short*)alloc((size_t)8 * 1156 * 256 * 2);
  unsigned short* L0in = (unsigned short*)alloc((size_t)2 * 4 * 400 * 640 * 2);
  unsigned short* L1in = (unsigned short*)alloc((size_t)2 * 4 * 400 * 192 * 2);
  unsigned short* L2in = (unsigned short*)alloc((size_t)2 * 4 * 400 * 128 * 2);
  float* pp  = (float*)alloc((size_t)10 * 4 * 256 * 512 * 4);
  float* cT0 = (float*)alloc((size_t)4 * 256 * 128 * 4);
  float* cT1 = (float*)alloc((size_t)4 * 256 * 64 * 4);
  float* cT2 = (float*)alloc((size_t)4 * 256 * 64 * 4);
  unsigned short* wb2  = (unsigned short*)alloc((size_t)16 * 64 * 32 * 2);
  unsigned short* wb3  = (unsigned short*)alloc((size_t)16 * 128 * 64 * 2);
  unsigned short* wb4  = (unsigned short*)alloc((size_t)16 * 256 * 128 * 2);
  unsigned short* wb5  = (unsigned short*)alloc((size_t)16 * 512 * 256 * 2);
  unsigned short* wbf0 = (unsigned short*)alloc((size_t)25 * 512 * 640 * 2);
  unsigned short* wbf1 = (unsigned short*)alloc((size_t)25 * 256 * 192 * 2);
  unsigned short* wbf2 = (unsigned short*)alloc((size_t)25 * 256 * 128 * 2);
  float* part  = (float*)alloc(262144);
  float* stats = (float*)alloc(4096);

  // ---- zero padded buffers (borders/h0) + c-state ----
  hipMemsetAsync(T2, 0, (size_t)8 * 66564 * 32 * 2, stream);
  hipMemsetAsync(T3, 0, (size_t)8 * 16900 * 64 * 2, stream);
  hipMemsetAsync(T4, 0, (size_t)8 * 4356 * 128 * 2, stream);
  hipMemsetAsync(T5, 0, (size_t)8 * 1156 * 256 * 2, stream);
  hipMemsetAsync(L0in, 0, (size_t)2 * 4 * 400 * 640 * 2, stream);
  hipMemsetAsync(L1in, 0, (size_t)2 * 4 * 400 * 192 * 2, stream);
  hipMemsetAsync(L2in, 0, (size_t)2 * 4 * 400 * 128 * 2, stream);
  hipMemsetAsync(cT0, 0, (size_t)4 * 256 * 128 * 4, stream);
  hipMemsetAsync(cT1, 0, (size_t)4 * 256 * 64 * 4, stream);
  hipMemsetAsync(cT2, 0, (size_t)4 * 256 * 64 * 4, stream);

  // ---- weight prep ----
  wprep_kernel<<<(64 * 32 * 16 + 255) / 256, 256, 0, stream>>>(c2w, wb2, 64, 32, 16);
  wprep_kernel<<<(128 * 64 * 16 + 255) / 256, 256, 0, stream>>>(c3w, wb3, 128, 64, 16);
  wprep_kernel<<<(256 * 128 * 16 + 255) / 256, 256, 0, stream>>>(c4w, wb4, 256, 128, 16);
  wprep_kernel<<<(512 * 256 * 16 + 255) / 256, 256, 0, stream>>>(c5w, wb5, 512, 256, 16);
  wprep_kernel<<<(512 * 640 * 25 + 255) / 256, 256, 0, stream>>>(lw0, wbf0, 512, 640, 25);
  wprep_kernel<<<(256 * 192 * 25 + 255) / 256, 256, 0, stream>>>(lw1, wbf1, 256, 192, 25);
  wprep_kernel<<<(256 * 128 * 25 + 255) / 256, 256, 0, stream>>>(lw2, wbf2, 256, 128, 25);

  // ---- stage 1: conv1 + fused partials; cbn -> T2 ----
  conv1_kernel<<<dim3(64, 8), 256, 0, stream>>>(h, c1w, x1T, part);
  fin_kernel<<<1, 64, 0, stream>>>(part, stats, 32, 512, 1.f / (float)(8 * 65536));
  cbn1T_kernel<<<dim3(256, 8), 256, 0, stream>>>(x1T, stats, e1, objs, T2);

  // ---- stage 2: 32 -> 64 @128 ----
  conv4T_kernel<32, 64, 128><<<dim3(1, 256, 8), 256, 0, stream>>>(T2, wb2, raw2);
  meanvarT_kernel<64><<<dim3(32, 8), 256, 0, stream>>>(raw2, part, 16384, 32);
  fin_kernel<<<1, 64, 0, stream>>>(part, stats, 64, 256, 1.f / (float)(8 * 16384));
  cbnT_kernel<64, 128, 1, 64, true, false><<<dim3(256, 8), 256, 0, stream>>>(raw2, stats, e2, objs, T3);

  // ---- stage 3: 64 -> 128 @64 ----
  conv4T_kernel<64, 128, 64><<<dim3(2, 64, 8), 256, 0, stream>>>(T3, wb3, raw3);
  meanvarT_kernel<128><<<dim3(8, 8), 256, 0, stream>>>(raw3, part, 4096, 8);
  fin_kernel<<<2, 64, 0, stream>>>(part, stats, 128, 64, 1.f / (float)(8 * 4096));
  cbnT_kernel<128, 64, 1, 128, true, false><<<dim3(64, 8), 256, 0, stream>>>(raw3, stats, e3, objs, T4);

  // ---- stage 4: 128 -> 256 @32 (no lrelu) ----
  conv4T_kernel<128, 256, 32><<<dim3(4, 16, 8), 256, 0, stream>>>(T4, wb4, raw4);
  meanvarT_kernel<256><<<dim3(4, 8), 256, 0, stream>>>(raw4, part, 1024, 4);
  fin_kernel<<<4, 64, 0, stream>>>(part, stats, 256, 32, 1.f / (float)(8 * 1024));
  cbnT_kernel<256, 32, 1, 256, false, false><<<dim3(16, 8), 256, 0, stream>>>(raw4, stats, e4, objs, T5);

  // ---- stage 5: 256 -> 512 @16 (no lrelu); cbn -> L0in x-slice (LSTM map) ----
  conv4T_kernel<256, 512, 16><<<dim3(8, 4, 8), 256, 0, stream>>>(T5, wb5, raw5);
  meanvarT_kernel<512><<<dim3(1, 8), 256, 0, stream>>>(raw5, part, 256, 1);
  fin_kernel<<<8, 64, 0, stream>>>(part, stats, 512, 8, 1.f / (float)(8 * 256));
  cbnT_kernel<512, 16, 2, 640, false, true><<<dim3(4, 8), 256, 0, stream>>>(raw5, stats, e5, objs, L0in);

  // ---- ConvLSTM 0: C=640 -> 128 ----
  for (int t = 0; t < 2; ++t) {
    conv5L_kernel<512, 640, 640, 2, 2, 2><<<dim3(8, 4, 10), 256, 0, stream>>>(
        L0in + (size_t)t * 4 * 400 * 640, wbf0, pp);
    lstm_pointT_kernel<128, 640, 512, 192><<<128, 256, 0, stream>>>(
        pp, 10, lb0, cT0,
        (t == 0) ? L0in + (size_t)4 * 400 * 640 : nullptr,
        L1in + (size_t)t * 4 * 400 * 192, nullptr);
  }

  // ---- ConvLSTM 1: C=192 -> 64 ----
  for (int t = 0; t < 2; ++t) {
    conv5L_kernel<256, 192, 192, 1, 4, 1><<<dim3(8, 4, 6), 256, 0, stream>>>(
        L1in + (size_t)t * 4 * 400 * 192, wbf1, pp);
    lstm_pointT_kernel<64, 192, 128, 128><<<64, 256, 0, stream>>>(
        pp, 6, lb1, cT1,
        (t == 0) ? L1in + (size_t)4 * 400 * 192 : nullptr,
        L2in + (size_t)t * 4 * 400 * 128, nullptr);
  }

  // ---- ConvLSTM 2: C=128 -> 64, final h -> d_out ----
  for (int t = 0; t < 2; ++t) {
    conv5L_kernel<256, 128, 128, 1, 4, 1><<<dim3(8, 4, 4), 256, 0, stream>>>(
        L2in + (size_t)t * 4 * 400 * 128, wbf2, pp);
    lstm_pointT_kernel<64, 128, 64, 1><<<64, 256, 0, stream>>>(
        pp, 4, lb2, cT2,
        (t == 0) ? L2in + (size_t)4 * 400 * 128 : nullptr,
        nullptr, (t == 1) ? (float*)d_out : nullptr);
  }
}

// Round 5
// 1418.246 us; speedup vs baseline: 8.6416x; 8.6416x over previous
//
#include <hip/hip_runtime.h>
#include <math.h>

#define LEAK 0.2f

typedef __attribute__((ext_vector_type(8))) short bf16x8;
typedef __attribute__((ext_vector_type(4))) float f32x4;

__device__ __forceinline__ unsigned short f2bf(float f) {
  unsigned u = __float_as_uint(f);
  u += 0x7FFFu + ((u >> 16) & 1u);
  return (unsigned short)(u >> 16);
}
__device__ __forceinline__ float bf2f(unsigned short s) {
  return __uint_as_float(((unsigned)s) << 16);
}
__device__ __forceinline__ unsigned pack2(float a, float b) {
  return (unsigned)f2bf(a) | ((unsigned)f2bf(b) << 16);
}

#define MFMA16(a, b, c) __builtin_amdgcn_mfma_f32_16x16x32_bf16(a, b, c, 0, 0, 0)

// ============================================================================
// conv1: 1x1 conv 512->32 on 254x254. Output TRANSPOSED f32 [n][254*254][32]
// + fused per-channel partial sums (strip = n*64 + blockIdx.x, S=512).
// NOTE: all acc[][] accesses must be compile-time-constant indexed (rule #20);
// R4's &acc cast + partial unroll sent acc to scratch -> 52 GB HBM traffic.
// ============================================================================
__global__ __launch_bounds__(256) void conv1_kernel(
    const float* __restrict__ h, const float* __restrict__ w,
    float* __restrict__ xT, float* __restrict__ part)
{
  __shared__ float wt[256 * 32];
  __shared__ float red[4][32][2];
  const int n  = blockIdx.y;
  const int r0 = blockIdx.x * 4;
  const int ix = threadIdx.x;
  const bool lanev = (ix < 254);
  const bool rv2 = (r0 + 2) < 254, rv3 = (r0 + 3) < 254;

  float acc[4][32];
#pragma unroll
  for (int r = 0; r < 4; ++r)
#pragma unroll
    for (int o = 0; o < 32; ++o) acc[r][o] = 0.f;

  const float* hp = h + (size_t)n * 512 * 64516 + (size_t)r0 * 254 + ix;

  for (int half = 0; half < 2; ++half) {
    const int cbase = half * 256;
    for (int i = threadIdx.x; i < 256 * 32; i += 256) {
      int c = i >> 5, o = i & 31;
      wt[i] = w[(size_t)o * 512 + cbase + c];
    }
    __syncthreads();
    if (lanev) {
#pragma unroll 4
      for (int c = 0; c < 256; ++c) {
        const float* pc = hp + (size_t)(cbase + c) * 64516;
        float vr[4];
        vr[0] = pc[0];
        vr[1] = pc[254];
        vr[2] = rv2 ? pc[2 * 254] : 0.f;
        vr[3] = rv3 ? pc[3 * 254] : 0.f;
        const float4* wp = (const float4*)&wt[c * 32];
#pragma unroll
        for (int q = 0; q < 8; ++q) {
          float4 w4 = wp[q];
#pragma unroll
          for (int r = 0; r < 4; ++r) {
            acc[r][4 * q + 0] = fmaf(vr[r], w4.x, acc[r][4 * q + 0]);
            acc[r][4 * q + 1] = fmaf(vr[r], w4.y, acc[r][4 * q + 1]);
            acc[r][4 * q + 2] = fmaf(vr[r], w4.z, acc[r][4 * q + 2]);
            acc[r][4 * q + 3] = fmaf(vr[r], w4.w, acc[r][4 * q + 3]);
          }
        }
      }
    }
    __syncthreads();
  }

  // write transposed: xT[n][(row*254+col)][32] — float4 built by value,
  // constant indices only (keeps acc in VGPRs).
  if (lanev) {
#pragma unroll
    for (int r = 0; r < 4; ++r) {
      if (r0 + r < 254) {
        float4* dst = (float4*)(xT + ((size_t)n * 64516 + (size_t)(r0 + r) * 254 + ix) * 32);
#pragma unroll
        for (int q = 0; q < 8; ++q)
          dst[q] = make_float4(acc[r][4 * q + 0], acc[r][4 * q + 1],
                               acc[r][4 * q + 2], acc[r][4 * q + 3]);
      }
    }
  }

  // fused per-channel partial sums; FULL unroll (constant acc indices).
  const int wv = ix >> 6;
#pragma unroll
  for (int o = 0; o < 32; ++o) {
    float s = acc[0][o] + acc[1][o] + acc[2][o] + acc[3][o];
    float q = acc[0][o] * acc[0][o] + acc[1][o] * acc[1][o]
            + acc[2][o] * acc[2][o] + acc[3][o] * acc[3][o];
#pragma unroll
    for (int off = 32; off; off >>= 1) {
      s += __shfl_down(s, off);
      q += __shfl_down(q, off);
    }
    if ((ix & 63) == 0) { red[wv][o][0] = s; red[wv][o][1] = q; }
  }
  __syncthreads();
  if (ix < 32) {
    float s = red[0][ix][0] + red[1][ix][0] + red[2][ix][0] + red[3][ix][0];
    float q = red[0][ix][1] + red[1][ix][1] + red[2][ix][1] + red[3][ix][1];
    const int strip = n * 64 + blockIdx.x;
    part[((size_t)ix * 512 + strip) * 2]     = s;
    part[((size_t)ix * 512 + strip) * 2 + 1] = q;
  }
}

// ============================================================================
// cbn1T: normalize conv1 output (incl. the 256^2 zero ring!) and write padded
// transposed bf16 T2 [n][258*258][32].
// ============================================================================
__global__ __launch_bounds__(256) void cbn1T_kernel(
    const float* __restrict__ xT, const float* __restrict__ stats,
    const float* __restrict__ e1, const int* __restrict__ objs,
    unsigned short* __restrict__ T2)
{
  __shared__ float st[32][4];
  const int n = blockIdx.y;
  if (threadIdx.x < 32) {
    int y = objs[n];
    st[threadIdx.x][0] = stats[threadIdx.x];
    st[threadIdx.x][1] = stats[32 + threadIdx.x];
    st[threadIdx.x][2] = e1[(size_t)y * 64 + threadIdx.x];
    st[threadIdx.x][3] = e1[(size_t)y * 64 + 32 + threadIdx.x];
  }
  __syncthreads();
  const int pix = blockIdx.x * 256 + threadIdx.x;   // 0..65535 over 256^2
  const int r = pix >> 8, c = pix & 255;
  const bool inter = (r >= 1 && r <= 254 && c >= 1 && c <= 254);
  const float* src = xT + ((size_t)n * 64516 + (size_t)(r - 1) * 254 + (c - 1)) * 32;
  unsigned short* dst = T2 + ((size_t)n * 66564 + (size_t)(r + 1) * 258 + (c + 1)) * 32;
  unsigned outw[16];
#pragma unroll
  for (int q = 0; q < 8; ++q) {
    float v[4];
    if (inter) { float4 t = ((const float4*)src)[q]; v[0]=t.x; v[1]=t.y; v[2]=t.z; v[3]=t.w; }
    else       { v[0]=v[1]=v[2]=v[3]=0.f; }
#pragma unroll
    for (int j = 0; j < 4; ++j) {
      int ch = q * 4 + j;
      float z = (v[j] - st[ch][0]) * st[ch][1] * st[ch][2] + st[ch][3];
      v[j] = z >= 0.f ? z : LEAK * z;
    }
    outw[2 * q]     = pack2(v[0], v[1]);
    outw[2 * q + 1] = pack2(v[2], v[3]);
  }
  uint4* d4 = (uint4*)dst;
#pragma unroll
  for (int q = 0; q < 4; ++q)
    d4[q] = make_uint4(outw[4*q], outw[4*q+1], outw[4*q+2], outw[4*q+3]);
}

// ============================================================================
// weight prep: [O][C][TAPS] f32 -> [tap][O][C] bf16
// ============================================================================
__global__ __launch_bounds__(256) void wprep_kernel(
    const float* __restrict__ w, unsigned short* __restrict__ dst, int O, int C, int TAPS)
{
  int i = blockIdx.x * 256 + threadIdx.x;
  int tot = O * C * TAPS;
  if (i < tot) {
    int o = i / (C * TAPS);
    int r = i - o * C * TAPS;
    int c = r / TAPS, tap = r - c * TAPS;
    dst[((size_t)tap * O + o) * C + c] = f2bf(w[i]);
  }
}

// ============================================================================
// conv4T: 4x4 stride-2 pad-1 conv, stage-free (B direct from padded bf16
// transposed input). Out: raw f32 [n][H*H][O].
// Block: 4 waves (2 wm x 2 wn), 64 o x 64 pixels. Grid (O/64, H*H/64, 8).
// ============================================================================
template <int C, int O, int H>
__global__ __launch_bounds__(256) void conv4T_kernel(
    const unsigned short* __restrict__ Tin, const unsigned short* __restrict__ wb,
    float* __restrict__ raw)
{
  constexpr int HIN2 = 2 * H + 2;
  constexpr int KC = C / 32;
  constexpr int LOGH = (H == 128 ? 7 : (H == 64 ? 6 : (H == 32 ? 5 : 4)));
  const int o0 = blockIdx.x * 64;
  const int strip = blockIdx.y;
  const int n = blockIdx.z;
  const int tid = threadIdx.x, lane = tid & 63, wid = tid >> 6;
  const int wm = wid >> 1, wn = wid & 1;
  const int ln15 = lane & 15, kg = lane >> 4;
  const unsigned short* inb = Tin + (size_t)n * (HIN2 * HIN2) * C;

  f32x4 acc[2][2];
#pragma unroll
  for (int m = 0; m < 2; ++m)
#pragma unroll
    for (int nt = 0; nt < 2; ++nt) acc[m][nt] = (f32x4){0.f, 0.f, 0.f, 0.f};

  const int gp0 = strip * 64 + (wn * 2 + 0) * 16;
  const int gp1 = strip * 64 + (wn * 2 + 1) * 16;
  const int r_0 = gp0 >> LOGH, c_0 = (gp0 & (H - 1)) + ln15;
  const int r_1 = gp1 >> LOGH, c_1 = (gp1 & (H - 1)) + ln15;

  for (int kc = 0; kc < KC; ++kc) {
    const int cb = kc * 32 + kg * 8;
#pragma unroll
    for (int tap = 0; tap < 16; ++tap) {
      const int ky = tap >> 2, kx = tap & 3;
      const unsigned short* ap = wb + ((size_t)tap * O + o0 + wm * 32 + ln15) * C + cb;
      bf16x8 a0 = *(const bf16x8*)ap;
      bf16x8 a1 = *(const bf16x8*)(ap + (size_t)16 * C);
      bf16x8 b0 = *(const bf16x8*)(inb + (size_t)((2 * r_0 + ky) * HIN2 + 2 * c_0 + kx) * C + cb);
      bf16x8 b1 = *(const bf16x8*)(inb + (size_t)((2 * r_1 + ky) * HIN2 + 2 * c_1 + kx) * C + cb);
      acc[0][0] = MFMA16(a0, b0, acc[0][0]);
      acc[1][0] = MFMA16(a1, b0, acc[1][0]);
      acc[0][1] = MFMA16(a0, b1, acc[0][1]);
      acc[1][1] = MFMA16(a1, b1, acc[1][1]);
    }
  }

#pragma unroll
  for (int mf = 0; mf < 2; ++mf) {
    const int o = o0 + wm * 32 + mf * 16 + kg * 4;
#pragma unroll
    for (int nt = 0; nt < 2; ++nt) {
      const int gp = strip * 64 + (wn * 2 + nt) * 16 + ln15;
      *(f32x4*)(raw + ((size_t)n * (H * H) + gp) * O + o) = acc[mf][nt];
    }
  }
}

// ============================================================================
// meanvarT: per-channel partial sums over raw f32 [n][npix][C].
// Grid (SPLITS, 8); strip s = n*SPLITS + bx; S = SPLITS*8.
// ============================================================================
template <int C>
__global__ __launch_bounds__(256) void meanvarT_kernel(
    const float* __restrict__ raw, float* __restrict__ part, int npix, int SPLITS)
{
  constexpr int C8 = C / 8, PL = 256 / C8;
  __shared__ float red[256][8][2];
  const int n = blockIdx.y, bx = blockIdx.x;
  const int c8 = threadIdx.x & (C8 - 1), pl = threadIdx.x / C8;
  const int LEN = npix / SPLITS;
  const int start = bx * LEN;
  const float* base = raw + (size_t)n * npix * C + c8 * 8;
  float s[8], q[8];
#pragma unroll
  for (int k = 0; k < 8; ++k) { s[k] = 0.f; q[k] = 0.f; }
  for (int i = start + pl; i < start + LEN; i += PL) {
    const float4* p = (const float4*)(base + (size_t)i * C);
    float4 v0 = p[0], v1 = p[1];
    float vv[8] = {v0.x, v0.y, v0.z, v0.w, v1.x, v1.y, v1.z, v1.w};
#pragma unroll
    for (int k = 0; k < 8; ++k) { s[k] += vv[k]; q[k] += vv[k] * vv[k]; }
  }
#pragma unroll
  for (int k = 0; k < 8; ++k) { red[threadIdx.x][k][0] = s[k]; red[threadIdx.x][k][1] = q[k]; }
  __syncthreads();
  const int S = SPLITS * 8;
  for (int c = threadIdx.x; c < C; c += 256) {
    int cc8 = c >> 3, k = c & 7;
    float ss = 0.f, qq = 0.f;
    for (int p2 = 0; p2 < PL; ++p2) {
      ss += red[p2 * C8 + cc8][k][0];
      qq += red[p2 * C8 + cc8][k][1];
    }
    const int sidx = n * SPLITS + bx;
    part[((size_t)c * S + sidx) * 2]     = ss;
    part[((size_t)c * S + sidx) * 2 + 1] = qq;
  }
}

// ---------------- finalize stats: part[C][S][2] -> stats[2][C] --------------
__global__ __launch_bounds__(64) void fin_kernel(
    const float* __restrict__ part, float* __restrict__ stats, int C, int S, float invN)
{
  int c = blockIdx.x * 64 + threadIdx.x;
  if (c >= C) return;
  float sum = 0.f, sq = 0.f;
  for (int s = 0; s < S; ++s) {
    sum += part[((size_t)c * S + s) * 2];
    sq  += part[((size_t)c * S + s) * 2 + 1];
  }
  float mean = sum * invN;
  float var = sq * invN - mean * mean;
  stats[c] = mean;
  stats[C + c] = rsqrtf(var + 1e-5f);
}

// ============================================================================
// cbnT: read raw f32 [n][H*H][C], normalize (+lrelu), write padded bf16
// [nmap][(H+2P)^2][CSO] at channel offset 0. Grid (H*H/64, 8).
// ============================================================================
template <int C, int H, int P2, int CSO, bool LRELU, bool LMAP>
__global__ __launch_bounds__(256) void cbnT_kernel(
    const float* __restrict__ raw, const float* __restrict__ stats,
    const float* __restrict__ embed, const int* __restrict__ objs,
    unsigned short* __restrict__ Tout)
{
  constexpr int W2 = H + 2 * P2;
  constexpr int LOGH = (H == 128 ? 7 : (H == 64 ? 6 : (H == 32 ? 5 : 4)));
  const int n = blockIdx.y;
  const int y = objs[n];
  const int pix = blockIdx.x * 64 + (threadIdx.x >> 2);
  const int r = pix >> LOGH, c = pix & (H - 1);
  const float* src = raw + ((size_t)n * (H * H) + pix) * C;
  const size_t nb = LMAP ? (size_t)((n & 1) * 4 + (n >> 1)) * (W2 * W2) * CSO
                         : (size_t)n * (W2 * W2) * CSO;
  unsigned short* dst = Tout + nb + ((size_t)(r + P2) * W2 + c + P2) * CSO;
  const float* gam = embed + (size_t)y * 2 * C;
  const float* bet = gam + C;
  for (int cs = (threadIdx.x & 3); cs < C / 8; cs += 4) {
    float4 m0 = ((const float4*)stats)[cs * 2],     m1 = ((const float4*)stats)[cs * 2 + 1];
    float4 s0 = ((const float4*)(stats + C))[cs * 2], s1 = ((const float4*)(stats + C))[cs * 2 + 1];
    float4 g0 = ((const float4*)gam)[cs * 2], g1 = ((const float4*)gam)[cs * 2 + 1];
    float4 b0 = ((const float4*)bet)[cs * 2], b1 = ((const float4*)bet)[cs * 2 + 1];
    float4 v0 = ((const float4*)src)[cs * 2], v1 = ((const float4*)src)[cs * 2 + 1];
    float o_[8];
    o_[0] = (v0.x - m0.x) * s0.x * g0.x + b0.x;
    o_[1] = (v0.y - m0.y) * s0.y * g0.y + b0.y;
    o_[2] = (v0.z - m0.z) * s0.z * g0.z + b0.z;
    o_[3] = (v0.w - m0.w) * s0.w * g0.w + b0.w;
    o_[4] = (v1.x - m1.x) * s1.x * g1.x + b1.x;
    o_[5] = (v1.y - m1.y) * s1.y * g1.y + b1.y;
    o_[6] = (v1.z - m1.z) * s1.z * g1.z + b1.z;
    o_[7] = (v1.w - m1.w) * s1.w * g1.w + b1.w;
    if (LRELU) {
#pragma unroll
      for (int k = 0; k < 8; ++k) o_[k] = o_[k] >= 0.f ? o_[k] : LEAK * o_[k];
    }
    ((uint4*)dst)[cs] = make_uint4(pack2(o_[0], o_[1]), pack2(o_[2], o_[3]),
                                   pack2(o_[4], o_[5]), pack2(o_[6], o_[7]));
  }
}

// ============================================================================
// conv5L: 5x5 s1 p2 conv on 16x16 (ConvLSTM), stage-free.
// Block: 4 waves = WM x WN over (WM*32 o) x 256 pixels. Grid (O/(WM*32), 4, KSPLIT).
// Out partials pp[ks][b][pix][O] f32.
// ============================================================================
template <int O, int C, int CS, int WM, int WN, int NCHUNK>
__global__ __launch_bounds__(256) void conv5L_kernel(
    const unsigned short* __restrict__ Lin, const unsigned short* __restrict__ wbf,
    float* __restrict__ pp)
{
  constexpr int FN = 16 / WN;
  const int o0 = blockIdx.x * (WM * 32);
  const int b = blockIdx.y, ks = blockIdx.z;
  const int tid = threadIdx.x, lane = tid & 63, wid = tid >> 6;
  const int wm = wid / WN, wn = wid % WN;
  const int ln15 = lane & 15, kg = lane >> 4;
  const unsigned short* inb = Lin + (size_t)b * 400 * CS;

  f32x4 acc[2][FN];
#pragma unroll
  for (int m = 0; m < 2; ++m)
#pragma unroll
    for (int nt = 0; nt < FN; ++nt) acc[m][nt] = (f32x4){0.f, 0.f, 0.f, 0.f};

  for (int kc = 0; kc < NCHUNK; ++kc) {
    const int cb = (ks * NCHUNK + kc) * 32 + kg * 8;
    for (int tap = 0; tap < 25; ++tap) {
      const int ty = tap / 5, tx = tap - 5 * ty;
      const unsigned short* ap = wbf + ((size_t)tap * O + o0 + wm * 32 + ln15) * C + cb;
      bf16x8 a0 = *(const bf16x8*)ap;
      bf16x8 a1 = *(const bf16x8*)(ap + (size_t)16 * C);
#pragma unroll
      for (int nt = 0; nt < FN; ++nt) {
        const int p = (wn * FN + nt) * 16 + ln15;
        const int prow = p >> 4, pcol = p & 15;
        bf16x8 bfv = *(const bf16x8*)(inb + (size_t)((prow + ty) * 20 + pcol + tx) * CS + cb);
        acc[0][nt] = MFMA16(a0, bfv, acc[0][nt]);
        acc[1][nt] = MFMA16(a1, bfv, acc[1][nt]);
      }
    }
  }

#pragma unroll
  for (int mf = 0; mf < 2; ++mf) {
    const int o = o0 + wm * 32 + mf * 16 + kg * 4;
#pragma unroll
    for (int nt = 0; nt < FN; ++nt) {
      const int pix = (wn * FN + nt) * 16 + ln15;
      *(f32x4*)(pp + (((size_t)(ks * 4 + b)) * 256 + pix) * O + o) = acc[mf][nt];
    }
  }
}

// ============================================================================
// lstm_pointT: sum K-partials, gates -> (c,h). h written as bf16 into the
// transposed padded buffers (own layer t+1 slot + next layer x slot), and/or
// f32 NCHW d_out. cT is f32 [b][pix][Hc].
// ============================================================================
template <int Hc, int CS, int CX, int CSN>
__global__ __launch_bounds__(256) void lstm_pointT_kernel(
    const float* __restrict__ pp, int KS, const float* __restrict__ bias,
    float* __restrict__ cT, unsigned short* __restrict__ own,
    unsigned short* __restrict__ nxt, float* __restrict__ fout)
{
  constexpr int C4 = Hc / 4;
  constexpr int O = 4 * Hc;
  constexpr int LOGC4 = (C4 == 32 ? 5 : 4);
  const int i = blockIdx.x * 256 + threadIdx.x;
  const int c4 = i & (C4 - 1);
  const int pix = (i >> LOGC4) & 255;
  const int b = i >> (LOGC4 + 8);

  float g[4][4];
#pragma unroll
  for (int gt = 0; gt < 4; ++gt)
#pragma unroll
    for (int j = 0; j < 4; ++j) g[gt][j] = 0.f;

  for (int ks = 0; ks < KS; ++ks) {
    const float* base = pp + (((size_t)(ks * 4 + b)) * 256 + pix) * O + c4 * 4;
#pragma unroll
    for (int gt = 0; gt < 4; ++gt) {
      float4 v = *(const float4*)(base + gt * Hc);
      g[gt][0] += v.x; g[gt][1] += v.y; g[gt][2] += v.z; g[gt][3] += v.w;
    }
  }
#pragma unroll
  for (int gt = 0; gt < 4; ++gt) {
    float4 bv = *(const float4*)(bias + gt * Hc + c4 * 4);
    g[gt][0] += bv.x; g[gt][1] += bv.y; g[gt][2] += bv.z; g[gt][3] += bv.w;
  }

  float* cp = cT + ((size_t)b * 256 + pix) * Hc + c4 * 4;
  float4 cold = *(const float4*)cp;
  float co[4] = {cold.x, cold.y, cold.z, cold.w};
  float hn[4];
#pragma unroll
  for (int j = 0; j < 4; ++j) {
    float si = 1.f / (1.f + expf(-g[0][j]));
    float sf = 1.f / (1.f + expf(-g[1][j]));
    float so = 1.f / (1.f + expf(-g[2][j]));
    float cn = sf * co[j] + si * tanhf(g[3][j]);
    co[j] = cn;
    hn[j] = so * tanhf(cn);
  }
  *(float4*)cp = make_float4(co[0], co[1], co[2], co[3]);

  const int prow = pix >> 4, pcol = pix & 15;
  const int ppix = (prow + 2) * 20 + pcol + 2;
  uint2 hb = make_uint2(pack2(hn[0], hn[1]), pack2(hn[2], hn[3]));
  if (own) *(uint2*)(own + ((size_t)b * 400 + ppix) * CS + CX + c4 * 4) = hb;
  if (nxt) *(uint2*)(nxt + ((size_t)b * 400 + ppix) * CSN + c4 * 4) = hb;
  if (fout) {
#pragma unroll
    for (int j = 0; j < 4; ++j)
      fout[((size_t)b * Hc + c4 * 4 + j) * 256 + pix] = hn[j];
  }
}

// ============================================================================
extern "C" void kernel_launch(void* const* d_in, const int* in_sizes, int n_in,
                              void* d_out, int out_size, void* d_ws, size_t ws_size,
                              hipStream_t stream)
{
  const float* h    = (const float*)d_in[0];
  const int*   objs = (const int*)  d_in[1];
  const float* c1w  = (const float*)d_in[3];
  const float* c2w  = (const float*)d_in[4];
  const float* c3w  = (const float*)d_in[5];
  const float* c4w  = (const float*)d_in[6];
  const float* c5w  = (const float*)d_in[7];
  const float* e1   = (const float*)d_in[8];
  const float* e2   = (const float*)d_in[9];
  const float* e3   = (const float*)d_in[10];
  const float* e4   = (const float*)d_in[11];
  const float* e5   = (const float*)d_in[12];
  const float* lw0  = (const float*)d_in[13];
  const float* lb0  = (const float*)d_in[14];
  const float* lw1  = (const float*)d_in[15];
  const float* lb1  = (const float*)d_in[16];
  const float* lw2  = (const float*)d_in[17];
  const float* lb2  = (const float*)d_in[18];

  char* p = (char*)d_ws;
  auto alloc = [&](size_t bytes) { char* r = p; p += (bytes + 255) & ~(size_t)255; return r; };
  float* x1T  = (float*)alloc((size_t)8 * 64516 * 32 * 4);
  float* raw2 = (float*)alloc((size_t)8 * 16384 * 64 * 4);
  float* raw3 = (float*)alloc((size_t)8 * 4096 * 128 * 4);
  float* raw4 = (float*)alloc((size_t)8 * 1024 * 256 * 4);
  float* raw5 = (float*)alloc((size_t)8 * 256 * 512 * 4);
  unsigned short* T2 = (unsigned short*)alloc((size_t)8 * 66564 * 32 * 2);
  unsigned short* T3 = (unsigned short*)alloc((size_t)8 * 16900 * 64 * 2);
  unsigned short* T4 = (unsigned short*)alloc((size_t)8 * 4356 * 128 * 2);
  unsigned short* T5 = (unsigned short*)alloc((size_t)8 * 1156 * 256 * 2);
  unsigned short* L0in = (unsigned short*)alloc((size_t)2 * 4 * 400 * 640 * 2);
  unsigned short* L1in = (unsigned short*)alloc((size_t)2 * 4 * 400 * 192 * 2);
  unsigned short* L2in = (unsigned short*)alloc((size_t)2 * 4 * 400 * 128 * 2);
  float* pp  = (float*)alloc((size_t)10 * 4 * 256 * 512 * 4);
  float* cT0 = (float*)alloc((size_t)4 * 256 * 128 * 4);
  float* cT1 = (float*)alloc((size_t)4 * 256 * 64 * 4);
  float* cT2 = (float*)alloc((size_t)4 * 256 * 64 * 4);
  unsigned short* wb2  = (unsigned short*)alloc((size_t)16 * 64 * 32 * 2);
  unsigned short* wb3  = (unsigned short*)alloc((size_t)16 * 128 * 64 * 2);
  unsigned short* wb4  = (unsigned short*)alloc((size_t)16 * 256 * 128 * 2);
  unsigned short* wb5  = (unsigned short*)alloc((size_t)16 * 512 * 256 * 2);
  unsigned short* wbf0 = (unsigned short*)alloc((size_t)25 * 512 * 640 * 2);
  unsigned short* wbf1 = (unsigned short*)alloc((size_t)25 * 256 * 192 * 2);
  unsigned short* wbf2 = (unsigned short*)alloc((size_t)25 * 256 * 128 * 2);
  float* part  = (float*)alloc(262144);
  float* stats = (float*)alloc(4096);

  // ---- zero padded buffers (borders/h0) + c-state ----
  hipMemsetAsync(T2, 0, (size_t)8 * 66564 * 32 * 2, stream);
  hipMemsetAsync(T3, 0, (size_t)8 * 16900 * 64 * 2, stream);
  hipMemsetAsync(T4, 0, (size_t)8 * 4356 * 128 * 2, stream);
  hipMemsetAsync(T5, 0, (size_t)8 * 1156 * 256 * 2, stream);
  hipMemsetAsync(L0in, 0, (size_t)2 * 4 * 400 * 640 * 2, stream);
  hipMemsetAsync(L1in, 0, (size_t)2 * 4 * 400 * 192 * 2, stream);
  hipMemsetAsync(L2in, 0, (size_t)2 * 4 * 400 * 128 * 2, stream);
  hipMemsetAsync(cT0, 0, (size_t)4 * 256 * 128 * 4, stream);
  hipMemsetAsync(cT1, 0, (size_t)4 * 256 * 64 * 4, stream);
  hipMemsetAsync(cT2, 0, (size_t)4 * 256 * 64 * 4, stream);

  // ---- weight prep ----
  wprep_kernel<<<(64 * 32 * 16 + 255) / 256, 256, 0, stream>>>(c2w, wb2, 64, 32, 16);
  wprep_kernel<<<(128 * 64 * 16 + 255) / 256, 256, 0, stream>>>(c3w, wb3, 128, 64, 16);
  wprep_kernel<<<(256 * 128 * 16 + 255) / 256, 256, 0, stream>>>(c4w, wb4, 256, 128, 16);
  wprep_kernel<<<(512 * 256 * 16 + 255) / 256, 256, 0, stream>>>(c5w, wb5, 512, 256, 16);
  wprep_kernel<<<(512 * 640 * 25 + 255) / 256, 256, 0, stream>>>(lw0, wbf0, 512, 640, 25);
  wprep_kernel<<<(256 * 192 * 25 + 255) / 256, 256, 0, stream>>>(lw1, wbf1, 256, 192, 25);
  wprep_kernel<<<(256 * 128 * 25 + 255) / 256, 256, 0, stream>>>(lw2, wbf2, 256, 128, 25);

  // ---- stage 1: conv1 + fused partials; cbn -> T2 ----
  conv1_kernel<<<dim3(64, 8), 256, 0, stream>>>(h, c1w, x1T, part);
  fin_kernel<<<1, 64, 0, stream>>>(part, stats, 32, 512, 1.f / (float)(8 * 65536));
  cbn1T_kernel<<<dim3(256, 8), 256, 0, stream>>>(x1T, stats, e1, objs, T2);

  // ---- stage 2: 32 -> 64 @128 ----
  conv4T_kernel<32, 64, 128><<<dim3(1, 256, 8), 256, 0, stream>>>(T2, wb2, raw2);
  meanvarT_kernel<64><<<dim3(32, 8), 256, 0, stream>>>(raw2, part, 16384, 32);
  fin_kernel<<<1, 64, 0, stream>>>(part, stats, 64, 256, 1.f / (float)(8 * 16384));
  cbnT_kernel<64, 128, 1, 64, true, false><<<dim3(256, 8), 256, 0, stream>>>(raw2, stats, e2, objs, T3);

  // ---- stage 3: 64 -> 128 @64 ----
  conv4T_kernel<64, 128, 64><<<dim3(2, 64, 8), 256, 0, stream>>>(T3, wb3, raw3);
  meanvarT_kernel<128><<<dim3(8, 8), 256, 0, stream>>>(raw3, part, 4096, 8);
  fin_kernel<<<2, 64, 0, stream>>>(part, stats, 128, 64, 1.f / (float)(8 * 4096));
  cbnT_kernel<128, 64, 1, 128, true, false><<<dim3(64, 8), 256, 0, stream>>>(raw3, stats, e3, objs, T4);

  // ---- stage 4: 128 -> 256 @32 (no lrelu) ----
  conv4T_kernel<128, 256, 32><<<dim3(4, 16, 8), 256, 0, stream>>>(T4, wb4, raw4);
  meanvarT_kernel<256><<<dim3(4, 8), 256, 0, stream>>>(raw4, part, 1024, 4);
  fin_kernel<<<4, 64, 0, stream>>>(part, stats, 256, 32, 1.f / (float)(8 * 1024));
  cbnT_kernel<256, 32, 1, 256, false, false><<<dim3(16, 8), 256, 0, stream>>>(raw4, stats, e4, objs, T5);

  // ---- stage 5: 256 -> 512 @16 (no lrelu); cbn -> L0in x-slice (LSTM map) ----
  conv4T_kernel<256, 512, 16><<<dim3(8, 4, 8), 256, 0, stream>>>(T5, wb5, raw5);
  meanvarT_kernel<512><<<dim3(1, 8), 256, 0, stream>>>(raw5, part, 256, 1);
  fin_kernel<<<8, 64, 0, stream>>>(part, stats, 512, 8, 1.f / (float)(8 * 256));
  cbnT_kernel<512, 16, 2, 640, false, true><<<dim3(4, 8), 256, 0, stream>>>(raw5, stats, e5, objs, L0in);

  // ---- ConvLSTM 0: C=640 -> 128 ----
  for (int t = 0; t < 2; ++t) {
    conv5L_kernel<512, 640, 640, 2, 2, 2><<<dim3(8, 4, 10), 256, 0, stream>>>(
        L0in + (size_t)t * 4 * 400 * 640, wbf0, pp);
    lstm_pointT_kernel<128, 640, 512, 192><<<128, 256, 0, stream>>>(
        pp, 10, lb0, cT0,
        (t == 0) ? L0in + (size_t)4 * 400 * 640 : nullptr,
        L1in + (size_t)t * 4 * 400 * 192, nullptr);
  }

  // ---- ConvLSTM 1: C=192 -> 64 ----
  for (int t = 0; t < 2; ++t) {
    conv5L_kernel<256, 192, 192, 1, 4, 1><<<dim3(8, 4, 6), 256, 0, stream>>>(
        L1in + (size_t)t * 4 * 400 * 192, wbf1, pp);
    lstm_pointT_kernel<64, 192, 128, 128><<<64, 256, 0, stream>>>(
        pp, 6, lb1, cT1,
        (t == 0) ? L1in + (size_t)4 * 400 * 192 : nullptr,
        L2in + (size_t)t * 4 * 400 * 128, nullptr);
  }

  // ---- ConvLSTM 2: C=128 -> 64, final h -> d_out ----
  for (int t = 0; t < 2; ++t) {
    conv5L_kernel<256, 128, 128, 1, 4, 1><<<dim3(8, 4, 4), 256, 0, stream>>>(
        L2in + (size_t)t * 4 * 400 * 128, wbf2, pp);
    lstm_pointT_kernel<64, 128, 64, 1><<<64, 256, 0, stream>>>(
        pp, 4, lb2, cT2,
        (t == 0) ? L2in + (size_t)4 * 400 * 128 : nullptr,
        nullptr, (t == 1) ? (float*)d_out : nullptr);
  }
}